// Round 1
// 392.928 us; speedup vs baseline: 1.0740x; 1.0740x over previous
//
#include <hip/hip_runtime.h>
#include <hip/hip_fp16.h>
#include <cstdint>
#include <cstddef>

#define M_DIM 8192
#define N_DIM 4096
#define K_DIM 4096

typedef int v4i __attribute__((ext_vector_type(4)));

// ---------------------------------------------------------------------------
// Fused pack kernel: int32 (harness-widened int8) -> int8 for BOTH x and w in
// one launch (saves one dispatch). 16B coalesced load -> 4B coalesced store.
// ---------------------------------------------------------------------------
__global__ __launch_bounds__(256) void pack_i32_to_i8(const int* __restrict__ srcX,
                                                      uint32_t* __restrict__ dstX,
                                                      const int* __restrict__ srcW,
                                                      uint32_t* __restrict__ dstW,
                                                      int nx4, int ntot) {
    int i = blockIdx.x * 256 + threadIdx.x;
    if (i >= ntot) return;
    const int* s;
    uint32_t*  d;
    int j;
    if (i < nx4) { s = srcX; d = dstX; j = i; }
    else         { s = srcW; d = dstW; j = i - nx4; }
    int4 a = ((const int4*)s)[j];
#if __has_builtin(__builtin_amdgcn_perm)
    uint32_t lo = __builtin_amdgcn_perm((uint32_t)a.y, (uint32_t)a.x, 0x0400);
    uint32_t hi = __builtin_amdgcn_perm((uint32_t)a.w, (uint32_t)a.z, 0x0400);
    d[j] = __builtin_amdgcn_perm(hi, lo, 0x05040100);
#else
    d[j] = (uint32_t)(a.x & 0xff) | ((uint32_t)(a.y & 0xff) << 8) |
           ((uint32_t)(a.z & 0xff) << 16) | ((uint32_t)a.w << 24);
#endif
}

__device__ __forceinline__ void gload_lds16(const int8_t* g, int8_t* l) {
    __builtin_amdgcn_global_load_lds(
        (const __attribute__((address_space(1))) void*)g,
        (__attribute__((address_space(3))) void*)l, 16, 0, 0);
}

// ---------------------------------------------------------------------------
// GEMM: C[m][n] = sum_k A[m][k]*W[n][k], int32 acc, fused dequant epilogue.
//
// ROUND 5 RESTRUCTURE: 256x256 tile, BK=64, 8 waves (2Mx4N), per-wave 128x64
// via acc[8][4] of mfma_i32_16x16x64_i8. 4 LDS K-tile buffers (4 x 32KB =
// 128KB) -> staging runs 3 K-tiles ahead with COUNTED vmcnt (never 0 in the
// main loop): steady-state gate is vmcnt(8) (12 outstanding, drain oldest
// tile's 4 loads), tail 8->4->0. Two phases per K-tile (m-half split), each:
//   {ds_read 8/4 x b128 | issue 2 global_load_lds} ; s_barrier ;
//   lgkmcnt(0)+sched_barrier ; setprio(1) ; 16 MFMA ; setprio(0) ; s_barrier
// This is the verified 8-phase template rhythm (T3+T4+T5) ported to int8.
//
// CHUNK-ROTATION SWIZZLE unchanged from round 4 (0 bank conflicts): LDS slot
// [row*64 + p*16] holds global k-chunk (p + (row>>1)) & 3. Rotation depends
// only on row parity bits -> invariant under +128-row staging half and the
// 256-row tile (wm*128, mi*16 are multiples of 8 rows). Staging per thread:
// 2 A-loads (rows srow, srow+128) in phase 1, 2 B-loads in phase 2; LDS dst
// linear t*16 (+8192 for the upper half) = wave-uniform base + lane*16.
//
// vmcnt ledger (per wave, 4 loads per K-tile):
//   prologue: stage tiles 0,1,2 (12 loads); vmcnt(8) -> tile0 landed; barrier
//   iter kt:  ph1 +2 (A of kt+3), ph2 +2 (B of kt+3) -> <=12 outstanding;
//             vmcnt(8) leaves tiles kt+2,kt+3 in flight, tile kt+1 landed;
//             barrier => ALL waves' kt+1 loads landed before next ph1 reads.
//   WAR on buf (kt+3)&3 == (kt-1)&3: tile kt-1's last ds_reads complete at
//   its ph2 lgkmcnt(0), all-waves by its final barrier < this iter. Safe.
// ---------------------------------------------------------------------------

#define VMW(n) asm volatile("s_waitcnt vmcnt(" #n ")" ::: "memory")

#define PH_MFMA(MBASE)                                                        \
    __builtin_amdgcn_s_setprio(1);                                            \
    _Pragma("unroll")                                                         \
    for (int mi = 0; mi < 4; ++mi) {                                          \
        _Pragma("unroll")                                                     \
        for (int ni = 0; ni < 4; ++ni)                                        \
            acc[(MBASE) + mi][ni] = __builtin_amdgcn_mfma_i32_16x16x64_i8(    \
                af[mi], bf[ni], acc[(MBASE) + mi][ni], 0, 0, 0);              \
    }                                                                         \
    __builtin_amdgcn_s_setprio(0);

#define KTILE(KT, DO_STAGE, VMSTMT)                                           \
    do {                                                                      \
        int8_t* bufA = lds + ((KT) & 3) * 32768;                              \
        int8_t* bufB = bufA + 16384;                                          \
        v4i af[4], bf[4];                                                     \
        /* ---- phase 1: A rows (wm*128 + 0..63), all B cols ---- */          \
        _Pragma("unroll")                                                     \
        for (int i = 0; i < 4; ++i) {                                         \
            af[i] = *(const v4i*)(bufA + aoff + i * 1024);                    \
            bf[i] = *(const v4i*)(bufB + boff + i * 1024);                    \
        }                                                                     \
        if (DO_STAGE) {                                                       \
            int8_t* sAb = lds + (((KT) + 3) & 3) * 32768;                     \
            gload_lds16(gA0 + ((KT) + 3) * 64, sAb + ldsoff);                 \
            gload_lds16(gA1 + ((KT) + 3) * 64, sAb + ldsoff + 8192);          \
        }                                                                     \
        __builtin_amdgcn_s_barrier();                                         \
        asm volatile("s_waitcnt lgkmcnt(0)" ::: "memory");                    \
        __builtin_amdgcn_sched_barrier(0);                                    \
        PH_MFMA(0)                                                            \
        __builtin_amdgcn_s_barrier();                                         \
        /* ---- phase 2: A rows (wm*128 + 64..127), reuse bf ---- */          \
        _Pragma("unroll")                                                     \
        for (int i = 0; i < 4; ++i)                                           \
            af[i] = *(const v4i*)(bufA + aoff + 4096 + i * 1024);             \
        if (DO_STAGE) {                                                       \
            int8_t* sBb = lds + (((KT) + 3) & 3) * 32768 + 16384;             \
            gload_lds16(gB0 + ((KT) + 3) * 64, sBb + ldsoff);                 \
            gload_lds16(gB1 + ((KT) + 3) * 64, sBb + ldsoff + 8192);          \
        }                                                                     \
        __builtin_amdgcn_s_barrier();                                         \
        asm volatile("s_waitcnt lgkmcnt(0)" ::: "memory");                    \
        __builtin_amdgcn_sched_barrier(0);                                    \
        PH_MFMA(4)                                                            \
        VMSTMT;                                                               \
        __builtin_amdgcn_s_barrier();                                         \
    } while (0)

__global__ __launch_bounds__(512, 2) void gemm_i8_dq(const int8_t* __restrict__ A,
                                                     const int8_t* __restrict__ W,
                                                     const float* __restrict__ sx,
                                                     const float* __restrict__ sw,
                                                     const float* __restrict__ bias,
                                                     float* __restrict__ out) {
    __shared__ __attribute__((aligned(16))) int8_t lds[131072];  // 4 bufs x (16KB A + 16KB B)

    const int t    = threadIdx.x;
    const int lane = t & 63;
    const int w    = t >> 6;          // 0..7
    const int wm   = w >> 2;          // 0..1  (M halves of the 256-row tile)
    const int wn   = w & 3;           // 0..3  (N quarters)

    // XCD swizzle: 512 blocks, 8 XCDs, each XCD owns an 8(M) x 8(N) patch.
    const int flat = blockIdx.y * 16 + blockIdx.x;   // 0..511
    const int xcd  = flat & 7;
    const int idx  = flat >> 3;                      // 0..63
    const int bm   = (xcd >> 1) * 8 + (idx & 7);     // 0..31
    const int bn   = (xcd & 1) * 8 + (idx >> 3);     // 0..15

    // ---- staging addresses (4 gload_lds/thread per K-tile: 2 A + 2 B) ----
    const int srow   = t >> 2;                       // 0..127
    const int rot    = (srow >> 1) & 3;
    const int gchunk = ((t & 3) + rot) & 3;          // rotated 16B chunk
    const int scol   = gchunk * 16;
    const int8_t* gA0 = A + (size_t)(bm * 256 + srow) * K_DIM + scol;
    const int8_t* gA1 = gA0 + (size_t)128 * K_DIM;
    const int8_t* gB0 = W + (size_t)(bn * 256 + srow) * K_DIM + scol;
    const int8_t* gB1 = gB0 + (size_t)128 * K_DIM;
    const int ldsoff = t * 16;                       // linear dst within region

    // ---- fragment read addresses (chunk-rotation inverse) ----
    const int rho  = lane & 15;
    const int p16  = (((lane >> 4) - (rho >> 1)) & 3) * 16;
    const int aoff = (wm * 128 + rho) * 64 + p16;
    const int boff = (wn * 64 + rho) * 64 + p16;

    v4i acc[8][4];
    const v4i vzero = {0, 0, 0, 0};
#pragma unroll
    for (int mi = 0; mi < 8; mi++)
#pragma unroll
        for (int ni = 0; ni < 4; ni++) acc[mi][ni] = vzero;

    // ---- prologue: stage K-tiles 0..2, gate tile 0, sync ----
#pragma unroll
    for (int pt = 0; pt < 3; ++pt) {
        int8_t* bufA = lds + pt * 32768;
        int8_t* bufB = bufA + 16384;
        gload_lds16(gA0 + pt * 64, bufA + ldsoff);
        gload_lds16(gA1 + pt * 64, bufA + ldsoff + 8192);
        gload_lds16(gB0 + pt * 64, bufB + ldsoff);
        gload_lds16(gB1 + pt * 64, bufB + ldsoff + 8192);
    }
    VMW(8);                           // tile 0 landed (tiles 1,2 in flight)
    __builtin_amdgcn_s_barrier();

    // ---- main loop: K_DIM/64 = 64 K-tiles; counted vmcnt, tail 8->4->0 ----
    for (int kt = 0; kt < 61; ++kt) KTILE(kt, true, VMW(8));
    KTILE(61, false, VMW(4));
    KTILE(62, false, VMW(0));
    KTILE(63, false, ((void)0));

    // ---- epilogue: C/D 16x16 layout: col = lane&15, row = (lane>>4)*4 + r --
    const float DIVF = (float)(1.0 / (127.0 * 127.0));
    const int col0 = bn * 256 + wn * 64 + (lane & 15);
    const int row0 = bm * 256 + wm * 128 + (lane >> 4) * 4;

    float swv[4], bv[4];
#pragma unroll
    for (int ni = 0; ni < 4; ni++) {
        swv[ni] = sw[col0 + ni * 16];
        bv[ni]  = bias[col0 + ni * 16];
    }

#pragma unroll
    for (int mi = 0; mi < 8; mi++) {
#pragma unroll
        for (int r = 0; r < 4; r++) {
            const int row = row0 + mi * 16 + r;
            const float xs = sx[row];
#pragma unroll
            for (int ni = 0; ni < 4; ni++) {
                // numpy op order: ((acc_f * DIV) * sx) * sw + bias, no fma
                float v = __fmul_rn((float)acc[mi][ni][r], DIVF);
                v = __fmul_rn(v, xs);
                v = __fmul_rn(v, swv[ni]);
                v = __fadd_rn(v, bv[ni]);
                out[(size_t)row * N_DIM + col0 + ni * 16] = __half2float(__float2half(v));
            }
        }
    }
}

extern "C" void kernel_launch(void* const* d_in, const int* in_sizes, int n_in,
                              void* d_out, int out_size, void* d_ws, size_t ws_size,
                              hipStream_t stream) {
    const int*   x_i32 = (const int*)d_in[0];      // [M,K] int (widened int8)
    const float* sx    = (const float*)d_in[1];    // [M] f32
    const int*   w_i32 = (const int*)d_in[2];      // [N,K] int (widened int8)
    const float* sw    = (const float*)d_in[3];    // [N] f32
    const float* bias  = (const float*)d_in[4];    // [N] f32 (widened fp16)
    float* out = (float*)d_out;                    // [M,N] f32 (widened fp16)

    uint8_t* xb = (uint8_t*)d_ws;                          // 32 MB packed x
    uint8_t* wb = (uint8_t*)d_ws + (size_t)M_DIM * K_DIM;  // 16 MB packed w

    const int nx4  = (M_DIM * K_DIM) / 4;
    const int nw4  = (N_DIM * K_DIM) / 4;
    const int ntot = nx4 + nw4;
    pack_i32_to_i8<<<(ntot + 255) / 256, 256, 0, stream>>>(
        x_i32, (uint32_t*)xb, w_i32, (uint32_t*)wb, nx4, ntot);

    dim3 grid(N_DIM / 256, M_DIM / 256);  // (16, 32) = 512 blocks
    gemm_i8_dq<<<grid, 512, 0, stream>>>((const int8_t*)xb, (const int8_t*)wb,
                                         sx, sw, bias, out);
}

// Round 2
// 386.630 us; speedup vs baseline: 1.0915x; 1.0163x over previous
//
#include <hip/hip_runtime.h>
#include <hip/hip_fp16.h>
#include <cstdint>
#include <cstddef>

#define M_DIM 8192
#define N_DIM 4096
#define K_DIM 4096

typedef int v4i __attribute__((ext_vector_type(4)));

// ---------------------------------------------------------------------------
// Fused pack kernel: int32 (harness-widened int8) -> int8 for BOTH x and w in
// one launch. 16B coalesced load -> 4B coalesced store.
// ---------------------------------------------------------------------------
__global__ __launch_bounds__(256) void pack_i32_to_i8(const int* __restrict__ srcX,
                                                      uint32_t* __restrict__ dstX,
                                                      const int* __restrict__ srcW,
                                                      uint32_t* __restrict__ dstW,
                                                      int nx4, int ntot) {
    int i = blockIdx.x * 256 + threadIdx.x;
    if (i >= ntot) return;
    const int* s;
    uint32_t*  d;
    int j;
    if (i < nx4) { s = srcX; d = dstX; j = i; }
    else         { s = srcW; d = dstW; j = i - nx4; }
    int4 a = ((const int4*)s)[j];
#if __has_builtin(__builtin_amdgcn_perm)
    uint32_t lo = __builtin_amdgcn_perm((uint32_t)a.y, (uint32_t)a.x, 0x0400);
    uint32_t hi = __builtin_amdgcn_perm((uint32_t)a.w, (uint32_t)a.z, 0x0400);
    d[j] = __builtin_amdgcn_perm(hi, lo, 0x05040100);
#else
    d[j] = (uint32_t)(a.x & 0xff) | ((uint32_t)(a.y & 0xff) << 8) |
           ((uint32_t)(a.z & 0xff) << 16) | ((uint32_t)a.w << 24);
#endif
}

__device__ __forceinline__ void gload_lds16(const int8_t* g, int8_t* l) {
    __builtin_amdgcn_global_load_lds(
        (const __attribute__((address_space(1))) void*)g,
        (__attribute__((address_space(3))) void*)l, 16, 0, 0);
}

// ---------------------------------------------------------------------------
// GEMM: C[m][n] = sum_k A[m][k]*W[n][k], int32 acc, fused dequant epilogue.
//
// 256x256 tile, BK=64, 8 waves (2Mx4N), per-wave 128x64 via acc[8][4] of
// mfma_i32_16x16x64_i8. 4 LDS K-tile buffers (128 KB), staging 3 K-tiles
// ahead, counted vmcnt(8) steady state (tail 8->4->0).
//
// ROUND 6: SINGLE-BARRIER K-TILE. Round 5's 4-barriers/K-tile + lgkmcnt(0)
// before each MFMA cluster lock-stepped all 8 waves: CU-wide LDS drain
// (~768 cy/K-tile) serialized with MFMA (~1306 cy/SIMD/K-tile) -> 41%
// MfmaUtil. The 4-buffer/3-ahead vmcnt ledger makes every cross-wave hazard
// safe with ONE barrier per K-tile:
//   - RAW (stage->read): my vmcnt(8) at end of iter kt-1 lands MY tile-kt
//     loads; the barrier makes ALL waves' tile-kt loads visible.
//   - WAR (read->overwrite): buf kt&3 is rewritten by staging of tile kt+4,
//     issued in iter kt+1, i.e. after the end-of-kt barrier; every wave's
//     tile-kt ds_reads are consumed by its MFMAs (compiler lgkm waits)
//     before it reaches that barrier. sched_barrier(0) fences both sides of
//     s_barrier (raw s_barrier has no implicit fence; loads are hoistable).
// No explicit lgkmcnt: compiler emits fine-grained counted waits before each
// MFMA group; with one sync point/tile, waves drift -> one wave's ds_reads
// drain under another's MFMAs (LDS || MFMA pipe overlap).
//
// CHUNK-ROTATION SWIZZLE unchanged (0 bank conflicts): LDS slot [row*64+p*16]
// holds global k-chunk (p + (row>>1)) & 3; fragment read inverts it.
// vmcnt ledger per wave (4 loads/K-tile): iter kt stages kt+3; end-of-iter
// outstanding <=12; vmcnt(8) -> tile kt+1 landed.
// ---------------------------------------------------------------------------

#define VMW(n) asm volatile("s_waitcnt vmcnt(" #n ")" ::: "memory")

#define KTILE(KT, DO_STAGE, VMSTMT, DO_SYNC)                                  \
    do {                                                                      \
        const int8_t* bufA = lds + ((KT) & 3) * 32768;                        \
        const int8_t* bufB = bufA + 16384;                                    \
        v4i af[4], bf[4], a2[4];                                              \
        _Pragma("unroll")                                                     \
        for (int i = 0; i < 4; ++i) {                                         \
            af[i] = *(const v4i*)(bufA + aoff + i * 1024);                    \
            bf[i] = *(const v4i*)(bufB + boff + i * 1024);                    \
        }                                                                     \
        _Pragma("unroll")                                                     \
        for (int i = 0; i < 4; ++i)                                           \
            a2[i] = *(const v4i*)(bufA + aoff + 4096 + i * 1024);             \
        if (DO_STAGE) {                                                       \
            int8_t* sAb = lds + (((KT) + 3) & 3) * 32768;                     \
            gload_lds16(gA0 + ((KT) + 3) * 64, sAb + ldsoff);                 \
            gload_lds16(gA1 + ((KT) + 3) * 64, sAb + ldsoff + 8192);          \
            gload_lds16(gB0 + ((KT) + 3) * 64, sAb + 16384 + ldsoff);         \
            gload_lds16(gB1 + ((KT) + 3) * 64, sAb + 16384 + ldsoff + 8192);  \
        }                                                                     \
        __builtin_amdgcn_s_setprio(1);                                        \
        _Pragma("unroll")                                                     \
        for (int mi = 0; mi < 4; ++mi) {                                      \
            _Pragma("unroll")                                                 \
            for (int ni = 0; ni < 4; ++ni)                                    \
                acc[mi][ni] = __builtin_amdgcn_mfma_i32_16x16x64_i8(          \
                    af[mi], bf[ni], acc[mi][ni], 0, 0, 0);                    \
        }                                                                     \
        _Pragma("unroll")                                                     \
        for (int mi = 0; mi < 4; ++mi) {                                      \
            _Pragma("unroll")                                                 \
            for (int ni = 0; ni < 4; ++ni)                                    \
                acc[4 + mi][ni] = __builtin_amdgcn_mfma_i32_16x16x64_i8(      \
                    a2[mi], bf[ni], acc[4 + mi][ni], 0, 0, 0);                \
        }                                                                     \
        __builtin_amdgcn_s_setprio(0);                                        \
        if (DO_SYNC) {                                                        \
            __builtin_amdgcn_sched_barrier(0);                                \
            VMSTMT;                                                           \
            __builtin_amdgcn_s_barrier();                                     \
            __builtin_amdgcn_sched_barrier(0);                                \
        }                                                                     \
    } while (0)

__global__ __launch_bounds__(512, 2) void gemm_i8_dq(const int8_t* __restrict__ A,
                                                     const int8_t* __restrict__ W,
                                                     const float* __restrict__ sx,
                                                     const float* __restrict__ sw,
                                                     const float* __restrict__ bias,
                                                     float* __restrict__ out) {
    __shared__ __attribute__((aligned(16))) int8_t lds[131072];  // 4 bufs x (16KB A + 16KB B)

    const int t    = threadIdx.x;
    const int lane = t & 63;
    const int w    = t >> 6;          // 0..7
    const int wm   = w >> 2;          // 0..1  (M halves of the 256-row tile)
    const int wn   = w & 3;           // 0..3  (N quarters)

    // XCD swizzle: 512 blocks, 8 XCDs, each XCD owns an 8(M) x 8(N) patch.
    const int flat = blockIdx.y * 16 + blockIdx.x;   // 0..511
    const int xcd  = flat & 7;
    const int idx  = flat >> 3;                      // 0..63
    const int bm   = (xcd >> 1) * 8 + (idx & 7);     // 0..31
    const int bn   = (xcd & 1) * 8 + (idx >> 3);     // 0..15

    // ---- staging addresses (4 gload_lds/thread per K-tile: 2 A + 2 B) ----
    const int srow   = t >> 2;                       // 0..127
    const int rot    = (srow >> 1) & 3;
    const int gchunk = ((t & 3) + rot) & 3;          // rotated 16B chunk
    const int scol   = gchunk * 16;
    const int8_t* gA0 = A + (size_t)(bm * 256 + srow) * K_DIM + scol;
    const int8_t* gA1 = gA0 + (size_t)128 * K_DIM;
    const int8_t* gB0 = W + (size_t)(bn * 256 + srow) * K_DIM + scol;
    const int8_t* gB1 = gB0 + (size_t)128 * K_DIM;
    const int ldsoff = t * 16;                       // linear dst within region

    // ---- fragment read addresses (chunk-rotation inverse) ----
    const int rho  = lane & 15;
    const int p16  = (((lane >> 4) - (rho >> 1)) & 3) * 16;
    const int aoff = (wm * 128 + rho) * 64 + p16;
    const int boff = (wn * 64 + rho) * 64 + p16;

    v4i acc[8][4];
    const v4i vzero = {0, 0, 0, 0};
#pragma unroll
    for (int mi = 0; mi < 8; mi++)
#pragma unroll
        for (int ni = 0; ni < 4; ni++) acc[mi][ni] = vzero;

    // ---- prologue: stage K-tiles 0..2, gate tile 0, sync ----
#pragma unroll
    for (int pt = 0; pt < 3; ++pt) {
        int8_t* bufA = lds + pt * 32768;
        int8_t* bufB = bufA + 16384;
        gload_lds16(gA0 + pt * 64, bufA + ldsoff);
        gload_lds16(gA1 + pt * 64, bufA + ldsoff + 8192);
        gload_lds16(gB0 + pt * 64, bufB + ldsoff);
        gload_lds16(gB1 + pt * 64, bufB + ldsoff + 8192);
    }
    VMW(8);                           // tile 0 landed (tiles 1,2 in flight)
    __builtin_amdgcn_s_barrier();
    __builtin_amdgcn_sched_barrier(0);

    // ---- main loop: 64 K-tiles; counted vmcnt, tail 8->4->0 ----
    for (int kt = 0; kt < 61; ++kt) KTILE(kt, true, VMW(8), true);
    KTILE(61, false, VMW(4), true);
    KTILE(62, false, VMW(0), true);
    KTILE(63, false, ((void)0), false);

    // ---- epilogue: C/D 16x16 layout: col = lane&15, row = (lane>>4)*4 + r --
    const float DIVF = (float)(1.0 / (127.0 * 127.0));
    const int col0 = bn * 256 + wn * 64 + (lane & 15);
    const int row0 = bm * 256 + wm * 128 + (lane >> 4) * 4;

    float swv[4], bv[4];
#pragma unroll
    for (int ni = 0; ni < 4; ni++) {
        swv[ni] = sw[col0 + ni * 16];
        bv[ni]  = bias[col0 + ni * 16];
    }

#pragma unroll
    for (int mi = 0; mi < 8; mi++) {
#pragma unroll
        for (int r = 0; r < 4; r++) {
            const int row = row0 + mi * 16 + r;
            const float xs = sx[row];
#pragma unroll
            for (int ni = 0; ni < 4; ni++) {
                // numpy op order: ((acc_f * DIV) * sx) * sw + bias, no fma
                float v = __fmul_rn((float)acc[mi][ni][r], DIVF);
                v = __fmul_rn(v, xs);
                v = __fmul_rn(v, swv[ni]);
                v = __fadd_rn(v, bv[ni]);
                out[(size_t)row * N_DIM + col0 + ni * 16] = __half2float(__float2half(v));
            }
        }
    }
}

extern "C" void kernel_launch(void* const* d_in, const int* in_sizes, int n_in,
                              void* d_out, int out_size, void* d_ws, size_t ws_size,
                              hipStream_t stream) {
    const int*   x_i32 = (const int*)d_in[0];      // [M,K] int (widened int8)
    const float* sx    = (const float*)d_in[1];    // [M] f32
    const int*   w_i32 = (const int*)d_in[2];      // [N,K] int (widened int8)
    const float* sw    = (const float*)d_in[3];    // [N] f32
    const float* bias  = (const float*)d_in[4];    // [N] f32 (widened fp16)
    float* out = (float*)d_out;                    // [M,N] f32 (widened fp16)

    uint8_t* xb = (uint8_t*)d_ws;                          // 32 MB packed x
    uint8_t* wb = (uint8_t*)d_ws + (size_t)M_DIM * K_DIM;  // 16 MB packed w

    const int nx4  = (M_DIM * K_DIM) / 4;
    const int nw4  = (N_DIM * K_DIM) / 4;
    const int ntot = nx4 + nw4;
    pack_i32_to_i8<<<(ntot + 255) / 256, 256, 0, stream>>>(
        x_i32, (uint32_t*)xb, w_i32, (uint32_t*)wb, nx4, ntot);

    dim3 grid(N_DIM / 256, M_DIM / 256);  // (16, 32) = 512 blocks
    gemm_i8_dq<<<grid, 512, 0, stream>>>((const int8_t*)xb, (const int8_t*)wb,
                                         sx, sw, bias, out);
}

// Round 4
// 383.764 us; speedup vs baseline: 1.0996x; 1.0075x over previous
//
#include <hip/hip_runtime.h>
#include <hip/hip_fp16.h>
#include <cstdint>
#include <cstddef>

#define M_DIM 8192
#define N_DIM 4096
#define K_DIM 4096

typedef int v4i __attribute__((ext_vector_type(4)));

// ---------------------------------------------------------------------------
// Fused pack kernel: int32 (harness-widened int8) -> int8 for BOTH x and w in
// one launch. 16B coalesced load -> 4B coalesced store.
// ---------------------------------------------------------------------------
__global__ __launch_bounds__(256) void pack_i32_to_i8(const int* __restrict__ srcX,
                                                      uint32_t* __restrict__ dstX,
                                                      const int* __restrict__ srcW,
                                                      uint32_t* __restrict__ dstW,
                                                      int nx4, int ntot) {
    int i = blockIdx.x * 256 + threadIdx.x;
    if (i >= ntot) return;
    const int* s;
    uint32_t*  d;
    int j;
    if (i < nx4) { s = srcX; d = dstX; j = i; }
    else         { s = srcW; d = dstW; j = i - nx4; }
    int4 a = ((const int4*)s)[j];
#if __has_builtin(__builtin_amdgcn_perm)
    uint32_t lo = __builtin_amdgcn_perm((uint32_t)a.y, (uint32_t)a.x, 0x0400);
    uint32_t hi = __builtin_amdgcn_perm((uint32_t)a.w, (uint32_t)a.z, 0x0400);
    d[j] = __builtin_amdgcn_perm(hi, lo, 0x05040100);
#else
    d[j] = (uint32_t)(a.x & 0xff) | ((uint32_t)(a.y & 0xff) << 8) |
           ((uint32_t)(a.z & 0xff) << 16) | ((uint32_t)a.w << 24);
#endif
}

__device__ __forceinline__ void gload_lds16(const int8_t* g, int8_t* l) {
    __builtin_amdgcn_global_load_lds(
        (const __attribute__((address_space(1))) void*)g,
        (__attribute__((address_space(3))) void*)l, 16, 0, 0);
}

// ---------------------------------------------------------------------------
// GEMM: C[m][n] = sum_k A[m][k]*W[n][k], int32 acc, fused dequant epilogue.
//
// 256x256 tile, BK=64, 8 waves (2Mx4N), per-wave 128x64 via acc[8][4] of
// mfma_i32_16x16x64_i8. 4 LDS K-tile buffers (128 KB), staging 3 K-tiles
// ahead via global_load_lds.
//
// ROUND 7/8: REGISTER-LEVEL 2-DEEP PIPELINE. Rounds 5/6 measured ~2740 cy
// per K-tile per CU = LDS drain (~1540 cy) fully SERIALIZED with MFMA
// (~1306 cy) — ds_reads and their consuming MFMAs were in the same iter.
// Fix: iter kt issues the 12 ds_reads for tile kt+1 into the alternate
// fragment set (P/Q, statically swapped via unroll x2), then MFMAs tile kt
// from the set read last iter. The LDS drain of kt+1 runs UNDER the MFMA of
// kt; compiler emits counted lgkmcnt(12) before the first MFMA (DS ops
// complete in-order per wave). sched_barrier(0) pins read/stage issue ahead
// of the MFMA cluster.
//
// vmcnt ledger (4 loads/tile; tile kt+1 is READ in iter kt, so it must be
// resident at the END of iter kt-1 — "landed one gate earlier"):
//   prologue: stage 0,1,2 (12 loads); gate vmcnt(4) -> tiles 0 AND 1 landed
//     (ROUND-8 FIX: was vmcnt(8) = only tile 0 -> iter 0's read of tile 1
//     raced its in-flight gload_lds writes -> absmax 4.8e-3 fail).
//   iter kt (kt<=60): stage kt+3 (outstanding <=8); gate vmcnt(4) drains
//     through tile kt+2 -> next iter's reads (tile kt+2) safe. Barrier ->
//     all waves' loads visible.
//   iter 61: no stage; gate vmcnt(0) -> tile 63 landed (read in iter 62).
//   iters 62,63: no stage, no gate/barrier (no LDS writes remain).
//   WAR: buf (kt+1)&3 is rewritten by stage of kt+5 (iter kt+2), one full
//   barrier after every wave's reads of it are lgkm-drained. Safe.
//
// CHUNK-ROTATION SWIZZLE unchanged (0 bank conflicts): LDS slot [row*64+p*16]
// holds global k-chunk (p + (row>>1)) & 3; fragment read inverts it.
// ---------------------------------------------------------------------------

#define VMW(n) asm volatile("s_waitcnt vmcnt(" #n ")" ::: "memory")

#define LOADF(DA, DB, DC, KT1)                                                \
    do {                                                                      \
        const int8_t* _b = lds + ((KT1) & 3) * 32768;                         \
        _Pragma("unroll")                                                     \
        for (int i = 0; i < 4; ++i) {                                         \
            DA[i] = *(const v4i*)(_b + aoff + i * 1024);                      \
            DB[i] = *(const v4i*)(_b + 16384 + boff + i * 1024);              \
            DC[i] = *(const v4i*)(_b + aoff + 4096 + i * 1024);               \
        }                                                                     \
    } while (0)

#define STAGE(KT3)                                                            \
    do {                                                                      \
        int8_t* _s = lds + ((KT3) & 3) * 32768;                               \
        gload_lds16(gA0 + (KT3) * 64, _s + ldsoff);                           \
        gload_lds16(gA1 + (KT3) * 64, _s + ldsoff + 8192);                    \
        gload_lds16(gB0 + (KT3) * 64, _s + 16384 + ldsoff);                   \
        gload_lds16(gB1 + (KT3) * 64, _s + 16384 + ldsoff + 8192);            \
    } while (0)

#define MFMA32(CA, CB, CC)                                                    \
    __builtin_amdgcn_s_setprio(1);                                            \
    _Pragma("unroll")                                                         \
    for (int mi = 0; mi < 4; ++mi) {                                          \
        _Pragma("unroll")                                                     \
        for (int ni = 0; ni < 4; ++ni)                                        \
            acc[mi][ni] = __builtin_amdgcn_mfma_i32_16x16x64_i8(              \
                CA[mi], CB[ni], acc[mi][ni], 0, 0, 0);                        \
    }                                                                         \
    _Pragma("unroll")                                                         \
    for (int mi = 0; mi < 4; ++mi) {                                          \
        _Pragma("unroll")                                                     \
        for (int ni = 0; ni < 4; ++ni)                                        \
            acc[4 + mi][ni] = __builtin_amdgcn_mfma_i32_16x16x64_i8(          \
                CC[mi], CB[ni], acc[4 + mi][ni], 0, 0, 0);                    \
    }                                                                         \
    __builtin_amdgcn_s_setprio(0);

// One K-tile iteration. CUR frags hold tile KT (read last iter); NXT frags
// receive tile KT+1. DOREAD/DOSTAGE/DOSYNC are compile-time constants.
#define ITER(KT, CA, CB, CC, NA, NB, NC, DOREAD, DOSTAGE, VMSTMT, DOSYNC)     \
    do {                                                                      \
        if (DOREAD) LOADF(NA, NB, NC, (KT) + 1);                              \
        if (DOSTAGE) STAGE((KT) + 3);                                         \
        __builtin_amdgcn_sched_barrier(0);  /* reads/stage issue first */     \
        MFMA32(CA, CB, CC);                                                   \
        if (DOSYNC) {                                                         \
            __builtin_amdgcn_sched_barrier(0);                                \
            VMSTMT;                                                           \
            __builtin_amdgcn_s_barrier();                                     \
            __builtin_amdgcn_sched_barrier(0);                                \
        }                                                                     \
    } while (0)

__global__ __launch_bounds__(512, 2) void gemm_i8_dq(const int8_t* __restrict__ A,
                                                     const int8_t* __restrict__ W,
                                                     const float* __restrict__ sx,
                                                     const float* __restrict__ sw,
                                                     const float* __restrict__ bias,
                                                     float* __restrict__ out) {
    __shared__ __attribute__((aligned(16))) int8_t lds[131072];  // 4 bufs x (16KB A + 16KB B)

    const int t    = threadIdx.x;
    const int lane = t & 63;
    const int w    = t >> 6;          // 0..7
    const int wm   = w >> 2;          // 0..1  (M halves of the 256-row tile)
    const int wn   = w & 3;           // 0..3  (N quarters)

    // XCD swizzle: 512 blocks, 8 XCDs, each XCD owns an 8(M) x 8(N) patch.
    const int flat = blockIdx.y * 16 + blockIdx.x;   // 0..511
    const int xcd  = flat & 7;
    const int idx  = flat >> 3;                      // 0..63
    const int bm   = (xcd >> 1) * 8 + (idx & 7);     // 0..31
    const int bn   = (xcd & 1) * 8 + (idx >> 3);     // 0..15

    // ---- staging addresses (4 gload_lds/thread per K-tile: 2 A + 2 B) ----
    const int srow   = t >> 2;                       // 0..127
    const int rot    = (srow >> 1) & 3;
    const int gchunk = ((t & 3) + rot) & 3;          // rotated 16B chunk
    const int scol   = gchunk * 16;
    const int8_t* gA0 = A + (size_t)(bm * 256 + srow) * K_DIM + scol;
    const int8_t* gA1 = gA0 + (size_t)128 * K_DIM;
    const int8_t* gB0 = W + (size_t)(bn * 256 + srow) * K_DIM + scol;
    const int8_t* gB1 = gB0 + (size_t)128 * K_DIM;
    const int ldsoff = t * 16;                       // linear dst within region

    // ---- fragment read addresses (chunk-rotation inverse) ----
    const int rho  = lane & 15;
    const int p16  = (((lane >> 4) - (rho >> 1)) & 3) * 16;
    const int aoff = (wm * 128 + rho) * 64 + p16;
    const int boff = (wn * 64 + rho) * 64 + p16;

    v4i acc[8][4];
    const v4i vzero = {0, 0, 0, 0};
#pragma unroll
    for (int mi = 0; mi < 8; mi++)
#pragma unroll
        for (int ni = 0; ni < 4; ni++) acc[mi][ni] = vzero;

    // Double-buffered fragment sets (statically swapped; no dynamic index).
    v4i pA[4], pB[4], pC[4], qA[4], qB[4], qC[4];

    // ---- prologue: stage K-tiles 0..2, land tiles 0 AND 1, read tile 0 ----
#pragma unroll
    for (int pt = 0; pt < 3; ++pt) {
        int8_t* bufA = lds + pt * 32768;
        gload_lds16(gA0 + pt * 64, bufA + ldsoff);
        gload_lds16(gA1 + pt * 64, bufA + ldsoff + 8192);
        gload_lds16(gB0 + pt * 64, bufA + 16384 + ldsoff);
        gload_lds16(gB1 + pt * 64, bufA + 16384 + ldsoff + 8192);
    }
    VMW(4);                           // tiles 0,1 landed (tile 2 in flight)
    __builtin_amdgcn_s_barrier();
    __builtin_amdgcn_sched_barrier(0);
    LOADF(pA, pB, pC, 0);             // tile-0 fragments -> P

    // ---- main loop: 64 K-tiles, unrolled x2 (P/Q swap) ----
    for (int kt = 0; kt < 60; kt += 2) {
        ITER(kt,     pA, pB, pC, qA, qB, qC, true, true, VMW(4), true);
        ITER(kt + 1, qA, qB, qC, pA, pB, pC, true, true, VMW(4), true);
    }
    ITER(60, pA, pB, pC, qA, qB, qC, true,  true,  VMW(4),  true);
    ITER(61, qA, qB, qC, pA, pB, pC, true,  false, VMW(0),  true);
    ITER(62, pA, pB, pC, qA, qB, qC, true,  false, ((void)0), false);
    ITER(63, qA, qB, qC, pA, pB, pC, false, false, ((void)0), false);

    // ---- epilogue: C/D 16x16 layout: col = lane&15, row = (lane>>4)*4 + r --
    const float DIVF = (float)(1.0 / (127.0 * 127.0));
    const int col0 = bn * 256 + wn * 64 + (lane & 15);
    const int row0 = bm * 256 + wm * 128 + (lane >> 4) * 4;

    float swv[4], bv[4];
#pragma unroll
    for (int ni = 0; ni < 4; ni++) {
        swv[ni] = sw[col0 + ni * 16];
        bv[ni]  = bias[col0 + ni * 16];
    }

#pragma unroll
    for (int mi = 0; mi < 8; mi++) {
#pragma unroll
        for (int r = 0; r < 4; r++) {
            const int row = row0 + mi * 16 + r;
            const float xs = sx[row];
#pragma unroll
            for (int ni = 0; ni < 4; ni++) {
                // numpy op order: ((acc_f * DIV) * sx) * sw + bias, no fma
                float v = __fmul_rn((float)acc[mi][ni][r], DIVF);
                v = __fmul_rn(v, xs);
                v = __fmul_rn(v, swv[ni]);
                v = __fadd_rn(v, bv[ni]);
                out[(size_t)row * N_DIM + col0 + ni * 16] = __half2float(__float2half(v));
            }
        }
    }
}

extern "C" void kernel_launch(void* const* d_in, const int* in_sizes, int n_in,
                              void* d_out, int out_size, void* d_ws, size_t ws_size,
                              hipStream_t stream) {
    const int*   x_i32 = (const int*)d_in[0];      // [M,K] int (widened int8)
    const float* sx    = (const float*)d_in[1];    // [M] f32
    const int*   w_i32 = (const int*)d_in[2];      // [N,K] int (widened int8)
    const float* sw    = (const float*)d_in[3];    // [N] f32
    const float* bias  = (const float*)d_in[4];    // [N] f32 (widened fp16)
    float* out = (float*)d_out;                    // [M,N] f32 (widened fp16)

    uint8_t* xb = (uint8_t*)d_ws;                          // 32 MB packed x
    uint8_t* wb = (uint8_t*)d_ws + (size_t)M_DIM * K_DIM;  // 16 MB packed w

    const int nx4  = (M_DIM * K_DIM) / 4;
    const int nw4  = (N_DIM * K_DIM) / 4;
    const int ntot = nx4 + nw4;
    pack_i32_to_i8<<<(ntot + 255) / 256, 256, 0, stream>>>(
        x_i32, (uint32_t*)xb, w_i32, (uint32_t*)wb, nx4, ntot);

    dim3 grid(N_DIM / 256, M_DIM / 256);  // (16, 32) = 512 blocks
    gemm_i8_dq<<<grid, 512, 0, stream>>>((const int8_t*)xb, (const int8_t*)wb,
                                         sx, sw, bias, out);
}

// Round 5
// 382.478 us; speedup vs baseline: 1.1033x; 1.0034x over previous
//
#include <hip/hip_runtime.h>
#include <hip/hip_fp16.h>
#include <cstdint>
#include <cstddef>

#define M_DIM 8192
#define N_DIM 4096
#define K_DIM 4096

typedef int v4i __attribute__((ext_vector_type(4)));
typedef __attribute__((address_space(3))) const int8_t* lds_cptr_t;

// ---------------------------------------------------------------------------
// Fused pack kernel: int32 (harness-widened int8) -> int8 for BOTH x and w in
// one launch. 16B coalesced load -> 4B coalesced store.
// ---------------------------------------------------------------------------
__global__ __launch_bounds__(256) void pack_i32_to_i8(const int* __restrict__ srcX,
                                                      uint32_t* __restrict__ dstX,
                                                      const int* __restrict__ srcW,
                                                      uint32_t* __restrict__ dstW,
                                                      int nx4, int ntot) {
    int i = blockIdx.x * 256 + threadIdx.x;
    if (i >= ntot) return;
    const int* s;
    uint32_t*  d;
    int j;
    if (i < nx4) { s = srcX; d = dstX; j = i; }
    else         { s = srcW; d = dstW; j = i - nx4; }
    int4 a = ((const int4*)s)[j];
#if __has_builtin(__builtin_amdgcn_perm)
    uint32_t lo = __builtin_amdgcn_perm((uint32_t)a.y, (uint32_t)a.x, 0x0400);
    uint32_t hi = __builtin_amdgcn_perm((uint32_t)a.w, (uint32_t)a.z, 0x0400);
    d[j] = __builtin_amdgcn_perm(hi, lo, 0x05040100);
#else
    d[j] = (uint32_t)(a.x & 0xff) | ((uint32_t)(a.y & 0xff) << 8) |
           ((uint32_t)(a.z & 0xff) << 16) | ((uint32_t)a.w << 24);
#endif
}

__device__ __forceinline__ void gload_lds16(const int8_t* g, int8_t* l) {
    __builtin_amdgcn_global_load_lds(
        (const __attribute__((address_space(1))) void*)g,
        (__attribute__((address_space(3))) void*)l, 16, 0, 0);
}

// ---------------------------------------------------------------------------
// GEMM: C[m][n] = sum_k A[m][k]*W[n][k], int32 acc, fused dequant epilogue.
//
// 256x256 tile, BK=64, 8 waves (2Mx4N), per-wave 128x64 via acc[8][4] of
// mfma_i32_16x16x64_i8. 4 LDS K-tile buffers (128 KB), staging 3 K-tiles
// ahead via global_load_lds, counted vmcnt (prologue 4; steady 4; tail 0).
//
// ROUND 9: MANUAL LGKM CONTROL (H1 test). Rounds 5-8 all landed at ~the
// serial sum of LDS drain (~1400 cy) + MFMA (~1306 cy) per K-tile despite
// source-level pipelining (r8: 2513 cy/tile measured vs 1540 overlapped
// model). Diagnosis: fragment reads were plain C++ LDS loads, so the
// COMPILER owned the lgkmcnt placement, and evidence says it emitted a
// conservative drain between the just-issued next-tile reads and the MFMA
// cluster (the ::: "memory" clobbers on my waitcnt asm likely fed that).
// Fix (HK/m214 pattern): fragment reads are inline-asm ds_read_b128 —
// OPAQUE to the waitcnt pass, which therefore inserts no waits for them —
// and the one counted wait is mine: after issuing tile kt+1's 12 reads,
//   s_waitcnt lgkmcnt(12)   // DS completes in-order -> oldest 12 = tile
//                           // kt's reads done; new 12 drain under MFMA
// followed by sched_barrier(0) (rule #18: MFMA must not hoist above an
// inline-asm wait). All waitcnt asm is BARE (no "memory" clobber), matching
// the verified m201 template. Iter 63 (no further reads) waits lgkmcnt(0).
//
// vmcnt ledger unchanged from round 8 (4 loads/tile; tile kt+1 is READ in
// iter kt => resident at END of iter kt-1):
//   prologue: stage 0,1,2; vmcnt(4) -> tiles 0 AND 1 landed; barrier.
//   iter kt<=60: stage kt+3; gate vmcnt(4) -> tile kt+2 landed; barrier.
//   iter 61: no stage; gate vmcnt(0). iters 62,63: no gate/barrier.
//   WAR: buf (kt+1)&3 rewritten by stage of kt+5 (iter kt+2), one barrier
//   after all waves' reads of it completed (lgkm in-order + LGW(12)). Safe.
//
// CHUNK-ROTATION SWIZZLE unchanged (0 bank conflicts): LDS slot [row*64+p*16]
// holds global k-chunk (p + (row>>1)) & 3; fragment read inverts it.
// ---------------------------------------------------------------------------

#define VMW(n) asm volatile("s_waitcnt vmcnt(" #n ")")
#define LGW(n) asm volatile("s_waitcnt lgkmcnt(" #n ")")

// Inline-asm LDS read, 16B, compile-time byte offset string (<65536).
#define DSR(dst, base, OFFSTR)                                                \
    asm volatile("ds_read_b128 %0, %1 offset:" OFFSTR : "=v"(dst) : "v"(base))

// 12 fragment reads for tile KT1 into (DA,DB,DC). Two base regs (A,B).
#define LOADF(DA, DB, DC, KT1)                                                \
    do {                                                                      \
        lds_cptr_t _ab = (lds_cptr_t)(lds + (((KT1) & 3) * 32768)) + aoff;    \
        lds_cptr_t _bb = (lds_cptr_t)(lds + (((KT1) & 3) * 32768 + 16384)) + boff; \
        DSR(DA[0], _ab, "0");    DSR(DB[0], _bb, "0");                        \
        DSR(DA[1], _ab, "1024"); DSR(DB[1], _bb, "1024");                     \
        DSR(DA[2], _ab, "2048"); DSR(DB[2], _bb, "2048");                     \
        DSR(DA[3], _ab, "3072"); DSR(DB[3], _bb, "3072");                     \
        DSR(DC[0], _ab, "4096"); DSR(DC[1], _ab, "5120");                     \
        DSR(DC[2], _ab, "6144"); DSR(DC[3], _ab, "7168");                     \
    } while (0)

#define STAGE(KT3)                                                            \
    do {                                                                      \
        int8_t* _s = lds + ((KT3) & 3) * 32768;                               \
        gload_lds16(gA0 + (KT3) * 64, _s + ldsoff);                           \
        gload_lds16(gA1 + (KT3) * 64, _s + ldsoff + 8192);                    \
        gload_lds16(gB0 + (KT3) * 64, _s + 16384 + ldsoff);                   \
        gload_lds16(gB1 + (KT3) * 64, _s + 16384 + ldsoff + 8192);            \
    } while (0)

#define MFMA32(CA, CB, CC)                                                    \
    __builtin_amdgcn_s_setprio(1);                                            \
    _Pragma("unroll")                                                         \
    for (int mi = 0; mi < 4; ++mi) {                                          \
        _Pragma("unroll")                                                     \
        for (int ni = 0; ni < 4; ++ni)                                        \
            acc[mi][ni] = __builtin_amdgcn_mfma_i32_16x16x64_i8(              \
                CA[mi], CB[ni], acc[mi][ni], 0, 0, 0);                        \
    }                                                                         \
    _Pragma("unroll")                                                         \
    for (int mi = 0; mi < 4; ++mi) {                                          \
        _Pragma("unroll")                                                     \
        for (int ni = 0; ni < 4; ++ni)                                        \
            acc[4 + mi][ni] = __builtin_amdgcn_mfma_i32_16x16x64_i8(          \
                CC[mi], CB[ni], acc[4 + mi][ni], 0, 0, 0);                    \
    }                                                                         \
    __builtin_amdgcn_s_setprio(0);

// One K-tile iteration. CUR frags (CA,CB,CC) hold tile KT, read last iter;
// NXT frags receive tile KT+1. LGSTMT: counted lgkm wait gating CUR.
#define ITER(KT, CA, CB, CC, NA, NB, NC, DOREAD, DOSTAGE, LGSTMT, VMSTMT, DOSYNC) \
    do {                                                                      \
        if (DOREAD) LOADF(NA, NB, NC, (KT) + 1);                              \
        if (DOSTAGE) STAGE((KT) + 3);                                         \
        __builtin_amdgcn_sched_barrier(0);                                    \
        LGSTMT;          /* oldest 12 DS (tile KT) complete; new 12 fly */    \
        __builtin_amdgcn_sched_barrier(0);                                    \
        MFMA32(CA, CB, CC);                                                   \
        if (DOSYNC) {                                                         \
            __builtin_amdgcn_sched_barrier(0);                                \
            VMSTMT;                                                           \
            __builtin_amdgcn_s_barrier();                                     \
            __builtin_amdgcn_sched_barrier(0);                                \
        }                                                                     \
    } while (0)

__global__ __launch_bounds__(512, 2) void gemm_i8_dq(const int8_t* __restrict__ A,
                                                     const int8_t* __restrict__ W,
                                                     const float* __restrict__ sx,
                                                     const float* __restrict__ sw,
                                                     const float* __restrict__ bias,
                                                     float* __restrict__ out) {
    __shared__ __attribute__((aligned(16))) int8_t lds[131072];  // 4 bufs x (16KB A + 16KB B)

    const int t    = threadIdx.x;
    const int lane = t & 63;
    const int w    = t >> 6;          // 0..7
    const int wm   = w >> 2;          // 0..1  (M halves of the 256-row tile)
    const int wn   = w & 3;           // 0..3  (N quarters)

    // XCD swizzle: 512 blocks, 8 XCDs, each XCD owns an 8(M) x 8(N) patch.
    const int flat = blockIdx.y * 16 + blockIdx.x;   // 0..511
    const int xcd  = flat & 7;
    const int idx  = flat >> 3;                      // 0..63
    const int bm   = (xcd >> 1) * 8 + (idx & 7);     // 0..31
    const int bn   = (xcd & 1) * 8 + (idx >> 3);     // 0..15

    // ---- staging addresses (4 gload_lds/thread per K-tile: 2 A + 2 B) ----
    const int srow   = t >> 2;                       // 0..127
    const int rot    = (srow >> 1) & 3;
    const int gchunk = ((t & 3) + rot) & 3;          // rotated 16B chunk
    const int scol   = gchunk * 16;
    const int8_t* gA0 = A + (size_t)(bm * 256 + srow) * K_DIM + scol;
    const int8_t* gA1 = gA0 + (size_t)128 * K_DIM;
    const int8_t* gB0 = W + (size_t)(bn * 256 + srow) * K_DIM + scol;
    const int8_t* gB1 = gB0 + (size_t)128 * K_DIM;
    const int ldsoff = t * 16;                       // linear dst within region

    // ---- fragment read addresses (chunk-rotation inverse) ----
    const int rho  = lane & 15;
    const int p16  = (((lane >> 4) - (rho >> 1)) & 3) * 16;
    const int aoff = (wm * 128 + rho) * 64 + p16;
    const int boff = (wn * 64 + rho) * 64 + p16;

    v4i acc[8][4];
    const v4i vzero = {0, 0, 0, 0};
#pragma unroll
    for (int mi = 0; mi < 8; mi++)
#pragma unroll
        for (int ni = 0; ni < 4; ni++) acc[mi][ni] = vzero;

    // Double-buffered fragment sets (statically swapped; no dynamic index).
    v4i pA[4], pB[4], pC[4], qA[4], qB[4], qC[4];

    // ---- prologue: stage K-tiles 0..2, land tiles 0 AND 1, read tile 0 ----
#pragma unroll
    for (int pt = 0; pt < 3; ++pt) {
        int8_t* bufA = lds + pt * 32768;
        gload_lds16(gA0 + pt * 64, bufA + ldsoff);
        gload_lds16(gA1 + pt * 64, bufA + ldsoff + 8192);
        gload_lds16(gB0 + pt * 64, bufA + 16384 + ldsoff);
        gload_lds16(gB1 + pt * 64, bufA + 16384 + ldsoff + 8192);
    }
    VMW(4);                           // tiles 0,1 landed (tile 2 in flight)
    __builtin_amdgcn_s_barrier();
    __builtin_amdgcn_sched_barrier(0);
    LOADF(pA, pB, pC, 0);             // tile-0 fragments -> P (12 DS in flight)

    // ---- main loop: 64 K-tiles, unrolled x2 (P/Q swap) ----
    for (int kt = 0; kt < 60; kt += 2) {
        ITER(kt,     pA, pB, pC, qA, qB, qC, true, true, LGW(12), VMW(4), true);
        ITER(kt + 1, qA, qB, qC, pA, pB, pC, true, true, LGW(12), VMW(4), true);
    }
    ITER(60, pA, pB, pC, qA, qB, qC, true,  true,  LGW(12), VMW(4),    true);
    ITER(61, qA, qB, qC, pA, pB, pC, true,  false, LGW(12), VMW(0),    true);
    ITER(62, pA, pB, pC, qA, qB, qC, true,  false, LGW(12), ((void)0), false);
    ITER(63, qA, qB, qC, pA, pB, pC, false, false, LGW(0),  ((void)0), false);

    // ---- epilogue: C/D 16x16 layout: col = lane&15, row = (lane>>4)*4 + r --
    const float DIVF = (float)(1.0 / (127.0 * 127.0));
    const int col0 = bn * 256 + wn * 64 + (lane & 15);
    const int row0 = bm * 256 + wm * 128 + (lane >> 4) * 4;

    float swv[4], bv[4];
#pragma unroll
    for (int ni = 0; ni < 4; ni++) {
        swv[ni] = sw[col0 + ni * 16];
        bv[ni]  = bias[col0 + ni * 16];
    }

#pragma unroll
    for (int mi = 0; mi < 8; mi++) {
#pragma unroll
        for (int r = 0; r < 4; r++) {
            const int row = row0 + mi * 16 + r;
            const float xs = sx[row];
#pragma unroll
            for (int ni = 0; ni < 4; ni++) {
                // numpy op order: ((acc_f * DIV) * sx) * sw + bias, no fma
                float v = __fmul_rn((float)acc[mi][ni][r], DIVF);
                v = __fmul_rn(v, xs);
                v = __fmul_rn(v, swv[ni]);
                v = __fadd_rn(v, bv[ni]);
                out[(size_t)row * N_DIM + col0 + ni * 16] = __half2float(__float2half(v));
            }
        }
    }
}

extern "C" void kernel_launch(void* const* d_in, const int* in_sizes, int n_in,
                              void* d_out, int out_size, void* d_ws, size_t ws_size,
                              hipStream_t stream) {
    const int*   x_i32 = (const int*)d_in[0];      // [M,K] int (widened int8)
    const float* sx    = (const float*)d_in[1];    // [M] f32
    const int*   w_i32 = (const int*)d_in[2];      // [N,K] int (widened int8)
    const float* sw    = (const float*)d_in[3];    // [N] f32
    const float* bias  = (const float*)d_in[4];    // [N] f32 (widened fp16)
    float* out = (float*)d_out;                    // [M,N] f32 (widened fp16)

    uint8_t* xb = (uint8_t*)d_ws;                          // 32 MB packed x
    uint8_t* wb = (uint8_t*)d_ws + (size_t)M_DIM * K_DIM;  // 16 MB packed w

    const int nx4  = (M_DIM * K_DIM) / 4;
    const int nw4  = (N_DIM * K_DIM) / 4;
    const int ntot = nx4 + nw4;
    pack_i32_to_i8<<<(ntot + 255) / 256, 256, 0, stream>>>(
        x_i32, (uint32_t*)xb, w_i32, (uint32_t*)wb, nx4, ntot);

    dim3 grid(N_DIM / 256, M_DIM / 256);  // (16, 32) = 512 blocks
    gemm_i8_dq<<<grid, 512, 0, stream>>>((const int8_t*)xb, (const int8_t*)wb,
                                         sx, sw, bias, out);
}